// Round 3
// 206.939 us; speedup vs baseline: 1.0363x; 1.0363x over previous
//
#include <hip/hip_runtime.h>

typedef _Float16 half8 __attribute__((ext_vector_type(8)));
typedef float floatx4 __attribute__((ext_vector_type(4)));

#define IMG   3136      // 56*56
#define PIMG  3364      // 58*58
#define XP_ELEMS (32 * 58 * 58 * 128)   // 13,778,944 fp16
#define WQ_ELEMS (9 * 256 * 128)        // 294,912 fp16

#define AS1 __attribute__((address_space(1)))
#define AS3 __attribute__((address_space(3)))

// ---------------- pre-pass: x NCHW fp32 -> zero-padded NHWC fp16 (unchanged) ----------
__global__ __launch_bounds__(256) void pad_x_kernel(const float* __restrict__ x,
                                                    _Float16* __restrict__ xp) {
    const int hh = blockIdx.x;          // 0..57
    const int n  = blockIdx.y;
    const int t  = threadIdx.x;
    _Float16* rowbase = xp + ((long)(n * 58 + hh) * 58) * 128;

    if (hh == 0 || hh == 57) {
        #pragma unroll
        for (int i = 0; i < 4; ++i) {
            int idx = i * 256 + t;
            if (idx < 928) *(half8*)(rowbase + idx * 8) = (half8)(_Float16)0.0f;
        }
        return;
    }

    __shared__ _Float16 tile[128 * 57];
    const int h = hh - 1;

    #pragma unroll
    for (int p = 0; p < 7; ++p) {
        int idx = p * 256 + t;              // 7*256 = 1792
        int c   = idx / 14;
        int w4  = (idx % 14) * 4;
        const float4 v = *(const float4*)(x + ((long)(n * 128 + c) * 56 + h) * 56 + w4);
        _Float16* d = tile + c * 57 + w4;
        d[0] = (_Float16)v.x; d[1] = (_Float16)v.y;
        d[2] = (_Float16)v.z; d[3] = (_Float16)v.w;
    }
    __syncthreads();

    #pragma unroll
    for (int p = 0; p < 4; ++p) {
        int idx = p * 256 + t;
        if (idx < 896) {
            int ww = idx >> 4;
            int c0 = (idx & 15) * 8;
            half8 v;
            #pragma unroll
            for (int j = 0; j < 8; ++j) v[j] = tile[(c0 + j) * 57 + ww];
            *(half8*)(rowbase + (ww + 1) * 128 + c0) = v;
        }
    }
    if (t < 32) {
        int ww = (t >> 4) ? 57 : 0;
        int c0 = (t & 15) * 8;
        *(half8*)(rowbase + ww * 128 + c0) = (half8)(_Float16)0.0f;
    }
}

// ---------------- pre-pass: W[k][c][r][s] fp32 -> round(W*128) fp16 [rs][k][c] ----------------
__global__ void quant_w_kernel(const float* __restrict__ W, _Float16* __restrict__ wq) {
    int t = blockIdx.x * 256 + threadIdx.x;     // 1152 * 256 = WQ_ELEMS
    int c  = t & 127;
    int k  = (t >> 7) & 255;
    int rs = t >> 15;
    wq[t] = (_Float16)rintf(W[(k * 128 + c) * 9 + rs] * 128.0f);
}

// ---------------- main: implicit GEMM, M=256, N=100352, K=1152 ----------------
// Geometry: BM=256 (all filters, by dim removed -> xp fetched ONCE), BN=128,
// BK=32, 4 waves in 2x2, wave tile 128x64 (8x4 mfma acc). Wave-tile arithmetic
// intensity Mw*Nw/(Mw+Nw) = 42.7 FLOP/LDS-byte (vs 32 at 64x64), and
// MFMA-per-barrier doubles (32/wave), attacking the LDS-pipe + barrier-overhead
// bound (MfmaUtil was 28% with LDS demand ~1.6x MFMA demand).
// Counted-vmcnt double-buffer loop: step s+1's 6 global_load_lds stay in
// flight across the barrier while step s computes (vmcnt(6), never 0).
// 36 K-steps: step t = (rs<<2)|cc, tap rs in [0,9), c-chunk cc in [0,4).
__global__ __launch_bounds__(256) void conv_mfma_kernel(
    const _Float16* __restrict__ xp, const _Float16* __restrict__ wq,
    const float* __restrict__ b, float* __restrict__ out)
{
    __shared__ __align__(16) _Float16 smem[24576];  // 2 x (A 8192 + B 4096) halves = 48 KB

    const int tid = threadIdx.x;
    const int l   = tid & 63;
    const int wv  = tid >> 6;
    const int wm  = wv & 1;         // filter half of tile (128 rows each)
    const int wn  = wv >> 1;        // pixel half of tile (64 cols each)
    const int bx  = blockIdx.x;     // pixel tile 0..783

    // staging: lane l -> LDS chunk (row = base + (l>>2), chunk_lds = l&3) holding
    // global chunk (l&3) ^ ((l>>3)&3)  (XOR swizzle keyed on row bits 1:2,
    // verified 0 bank conflicts in the 128x128 version; relation is row-base
    // invariant since key uses only row bits 1:2 and all row bases are x16)
    const int lrow = l >> 2;
    const int lch  = ((l & 3) ^ ((l >> 3) & 3)) * 8;

    // A tile: 256 rows x 32 halfs, staged as 4 wave-loads per wave
    int aoff[4];
    #pragma unroll
    for (int i = 0; i < 4; ++i)
        aoff[i] = (i * 64 + wv * 16 + lrow) * 128 + lch;

    // B tile: 128 pixel-rows x 32 halfs, 2 wave-loads per wave
    int pb[2];
    #pragma unroll
    for (int j = 0; j < 2; ++j) {
        const int pix = bx * 128 + j * 64 + wv * 16 + lrow;
        const int n  = pix / IMG, hw = pix % IMG;
        pb[j] = (n * PIMG + (hw / 56) * 58 + (hw % 56)) * 128 + lch;
    }

    const int stA = wv * 512;       // per-wave staging region (halfs)

    floatx4 acc[8][4] = {};

    // issue the 6 global_load_lds for K-step t into buffer pbuf
    auto issue = [&](int t, int pbuf) {
        const int rs = t >> 2;
        const int cc = t & 3;
        const int r  = (rs * 11) >> 5;          // rs/3 for rs in [0,9)
        const int s2 = rs - r * 3;
        const _Float16* wg = wq + rs * (256 * 128) + cc * 32;
        const _Float16* xg = xp + (r * 58 + s2) * 128 + cc * 32;
        _Float16* A = smem + pbuf * 12288;
        _Float16* B = A + 8192;
        #pragma unroll
        for (int i = 0; i < 4; ++i)
            __builtin_amdgcn_global_load_lds((AS1 void*)(wg + aoff[i]),
                                             (AS3 void*)(A + i * 2048 + stA), 16, 0, 0);
        #pragma unroll
        for (int j = 0; j < 2; ++j)
            __builtin_amdgcn_global_load_lds((AS1 void*)(xg + pb[j]),
                                             (AS3 void*)(B + j * 2048 + stA), 16, 0, 0);
    };

    const int ar = wm * 128 + (l & 15);
    const int br = wn * 64 + (l & 15);
    const int kq = ((l >> 4) ^ ((l >> 1) & 3)) * 8;   // read-side swizzle

    auto compute = [&](int pbuf) {
        const _Float16* As = smem + pbuf * 12288;
        const _Float16* Bs = As + 8192;
        half8 bf[4];
        #pragma unroll
        for (int ni = 0; ni < 4; ++ni)
            bf[ni] = *(const half8*)(Bs + (br + ni * 16) * 32 + kq);
        #pragma unroll
        for (int mi = 0; mi < 8; ++mi) {
            const half8 af = *(const half8*)(As + (ar + mi * 16) * 32 + kq);
            #pragma unroll
            for (int ni = 0; ni < 4; ++ni)
                acc[mi][ni] = __builtin_amdgcn_mfma_f32_16x16x32_f16(af, bf[ni], acc[mi][ni], 0, 0, 0);
        }
    };

    issue(0, 0);
    #pragma unroll 2
    for (int s = 0; s < 35; ++s) {
        issue(s + 1, (s + 1) & 1);
        // wait for step s's 6 loads (vmcnt retires in issue order), leaving
        // step s+1's 6 in flight across the barrier
        asm volatile("s_waitcnt vmcnt(6)" ::: "memory");
        asm volatile("s_barrier" ::: "memory");
        compute(s & 1);
        asm volatile("s_barrier" ::: "memory");   // readers done before s+2 overwrites
    }
    asm volatile("s_waitcnt vmcnt(0)" ::: "memory");
    asm volatile("s_barrier" ::: "memory");
    compute(1);   // step 35

    // epilogue: D[row=(l>>4)*4+reg = filter][col=l&15 = pixel]
    #pragma unroll
    for (int mi = 0; mi < 8; ++mi) {
        const int kb = wm * 128 + mi * 16 + (l >> 4) * 4;
        #pragma unroll
        for (int rg = 0; rg < 4; ++rg) {
            const int k = kb + rg;
            const float bq = rintf(b[k] * 128.0f);
            #pragma unroll
            for (int ni = 0; ni < 4; ++ni) {
                const int pix = bx * 128 + wn * 64 + ni * 16 + (l & 15);
                const int n  = pix / IMG;
                const int pr = pix - n * IMG;
                out[((long)n * 256 + k) * IMG + pr] = acc[mi][ni][rg] * (1.0f / 128.0f) + bq;
            }
        }
    }
}

// ---------------- fallback (ws too small): direct conv, correct but slow ----------------
__global__ void conv_fallback_kernel(const float* __restrict__ x, const float* __restrict__ W,
                                     const float* __restrict__ b, float* __restrict__ out)
{
    __shared__ float wsm[1152];
    const int k = blockIdx.y;
    for (int i = threadIdx.x; i < 1152; i += 256)
        wsm[i] = rintf(W[k * 1152 + i] * 128.0f);
    __syncthreads();
    const int pix = blockIdx.x * 256 + threadIdx.x;
    const int n = pix / IMG, hw = pix % IMG;
    const int h = hw / 56, w = hw % 56;
    float acc = 0.0f;
    for (int c = 0; c < 128; ++c) {
        const float* xr = x + ((n * 128 + c) * 56) * 56;
        const float* wr = wsm + c * 9;
        #pragma unroll
        for (int r = 0; r < 3; ++r) {
            const int hh = h + r - 1;
            if ((unsigned)hh >= 56u) continue;
            #pragma unroll
            for (int s = 0; s < 3; ++s) {
                const int ww = w + s - 1;
                if ((unsigned)ww >= 56u) continue;
                acc += xr[hh * 56 + ww] * wr[r * 3 + s];
            }
        }
    }
    out[((long)n * 256 + k) * IMG + hw] = acc * (1.0f / 128.0f) + rintf(b[k] * 128.0f);
}

extern "C" void kernel_launch(void* const* d_in, const int* in_sizes, int n_in,
                              void* d_out, int out_size, void* d_ws, size_t ws_size,
                              hipStream_t stream) {
    const float* x = (const float*)d_in[0];
    const float* W = (const float*)d_in[1];
    const float* b = (const float*)d_in[2];
    float* out = (float*)d_out;

    const size_t need = (size_t)XP_ELEMS * 2 + (size_t)WQ_ELEMS * 2;   // 28,147,712 B
    if (ws_size >= need) {
        _Float16* xp = (_Float16*)d_ws;
        _Float16* wq = xp + XP_ELEMS;
        pad_x_kernel<<<dim3(58, 32), 256, 0, stream>>>(x, xp);
        quant_w_kernel<<<WQ_ELEMS / 256, 256, 0, stream>>>(W, wq);
        conv_mfma_kernel<<<dim3(784), 256, 0, stream>>>(xp, wq, b, out);
    } else {
        conv_fallback_kernel<<<dim3(392, 256), 256, 0, stream>>>(x, W, b, out);
    }
}

// Round 4
// 204.391 us; speedup vs baseline: 1.0493x; 1.0125x over previous
//
#include <hip/hip_runtime.h>

typedef _Float16 half8 __attribute__((ext_vector_type(8)));
typedef float floatx4 __attribute__((ext_vector_type(4)));

#define IMG   3136      // 56*56
#define PIMG  3364      // 58*58
#define XP_ELEMS (32 * 58 * 58 * 128)   // 13,778,944 fp16
#define WQ_ELEMS (9 * 256 * 128)        // 294,912 fp16

#define AS1 __attribute__((address_space(1)))
#define AS3 __attribute__((address_space(3)))

// ---------------- merged pre-pass ----------------
// blocks [0,1856): x NCHW fp32 -> zero-padded NHWC fp16 (pad part, unchanged logic)
// blocks [1856,2000): W -> round(W*128) fp16 in STAGING-ORDER layout:
//   16B unit U: l=U&63, wv=(U>>6)&7, g=(U>>9)&1, h=(U>>10)&1, T=U>>11 (rs=T>>1,kt=T&1)
//   holds filters k=h*128+g*64+wv*8+(l>>3), channels c0=kt*64+((l&7)^((l>>3)&7))*8 .. +8
//   (chunk-XOR swizzle keyed on row&7 pre-applied so conv stages LINEARLY via global_load_lds)
__global__ __launch_bounds__(256) void prep_kernel(const float* __restrict__ x,
                                                   const float* __restrict__ W,
                                                   _Float16* __restrict__ xp,
                                                   _Float16* __restrict__ wq) {
    const int bid = blockIdx.x;
    const int t   = threadIdx.x;
    if (bid >= 1856) {
        // ---- quant part: 144 blocks, 36864 16B-units total ----
        int U = (bid - 1856) * 256 + t;
        int l  = U & 63;
        int wv = (U >> 6) & 7;
        int g  = (U >> 9) & 1;
        int h  = (U >> 10) & 1;
        int T  = U >> 11;                 // 0..17
        int rs = T >> 1, kt = T & 1;
        int k  = h * 128 + g * 64 + wv * 8 + (l >> 3);
        int c0 = kt * 64 + (((l & 7) ^ ((l >> 3) & 7)) * 8);
        _Float16* d = wq + (long)U * 8;
        #pragma unroll
        for (int j = 0; j < 8; ++j)
            d[j] = (_Float16)rintf(W[(k * 128 + c0 + j) * 9 + rs] * 128.0f);
        return;
    }
    // ---- pad part ----
    const int hh = bid % 58;
    const int n  = bid / 58;
    _Float16* rowbase = xp + ((long)(n * 58 + hh) * 58) * 128;

    if (hh == 0 || hh == 57) {
        #pragma unroll
        for (int i = 0; i < 4; ++i) {
            int idx = i * 256 + t;
            if (idx < 928) *(half8*)(rowbase + idx * 8) = (half8)(_Float16)0.0f;
        }
        return;
    }

    __shared__ _Float16 tile[128 * 57];
    const int h = hh - 1;

    #pragma unroll
    for (int p = 0; p < 7; ++p) {
        int idx = p * 256 + t;              // 7*256 = 1792
        int c   = idx / 14;
        int w4  = (idx % 14) * 4;
        const float4 v = *(const float4*)(x + ((long)(n * 128 + c) * 56 + h) * 56 + w4);
        _Float16* d = tile + c * 57 + w4;
        d[0] = (_Float16)v.x; d[1] = (_Float16)v.y;
        d[2] = (_Float16)v.z; d[3] = (_Float16)v.w;
    }
    __syncthreads();

    #pragma unroll
    for (int p = 0; p < 4; ++p) {
        int idx = p * 256 + t;
        if (idx < 896) {
            int ww = idx >> 4;
            int c0 = (idx & 15) * 8;
            half8 v;
            #pragma unroll
            for (int j = 0; j < 8; ++j) v[j] = tile[(c0 + j) * 57 + ww];
            *(half8*)(rowbase + (ww + 1) * 128 + c0) = v;
        }
    }
    if (t < 32) {
        int ww = (t >> 4) ? 57 : 0;
        int c0 = (t & 15) * 8;
        *(half8*)(rowbase + ww * 128 + c0) = (half8)(_Float16)0.0f;
    }
}

// ---------------- main: implicit GEMM, M=256, N=100352, K=1152 ----------------
// m201-class structure: BM=256, BN=256, BK=64, 512 threads = 8 waves (2M x 4N),
// wave tile 128x64 (8x4 acc), LDS 128 KB dbuf. 18 K-tiles (tap rs = T>>1,
// channel half kt = T&1). Per K-tile: 4 stage-phases (1 half-tile = 2
// global_load_lds each), ONE counted vmcnt (2 in steady state, 0 only at the
// last tile), 2 barriers. 64 MFMA/wave/K-tile in 4 quadrant clusters wrapped
// in setprio (T5 pays in phase-split schedules, m218b). Was 709 TF at the
// 2-phase structural ceiling (m230/m248: ~682); target m201-class (1563@4k).
__global__ __launch_bounds__(512, 2) void conv_mfma_kernel(
    const _Float16* __restrict__ xp, const _Float16* __restrict__ wq,
    const float* __restrict__ b, float* __restrict__ out)
{
    __shared__ __align__(16) _Float16 smem[65536];  // 2 bufs x (A 16384 + B 16384) = 128 KB

    const int tid = threadIdx.x;
    const int l   = tid & 63;
    const int wv  = tid >> 6;        // 0..7
    const int wm  = wv & 1;          // M-half (128 filters)
    const int wn  = wv >> 1;         // N-quarter (64 pixels)
    int bx  = blockIdx.x;
    bx = (bx & 7) * 49 + (bx >> 3);  // XCD swizzle (392 = 8*49, bijective)

    const int lr3  = l >> 3;
    const int l7   = l & 7;
    const int l47  = l >> 4;
    const int lswz = ((l & 7) ^ (lr3 & 7)) * 16;   // staged-chunk byte offset (XOR pre-swizzle)

    // B staging source bases: (h,g) -> pixel row = bx*256 + h*128 + g*64 + wv*8 + (l>>3)
    long pbB[4];
    #pragma unroll
    for (int hg = 0; hg < 4; ++hg) {
        const int pix = bx * 256 + hg * 64 + wv * 8 + lr3;
        const int n = pix / IMG, hw = pix % IMG;
        pbB[hg] = (long)(n * PIMG + (hw / 56) * 58 + (hw % 56)) * 256 + lswz;
    }
    // A staging source: wq flat pos = (((T*2+h)*2+g)*8 + wv)*1024 + l*16 bytes
    const long abase = (long)wv * 1024 + l * 16;

    floatx4 acc[8][4] = {};

    // stage one A half-tile (2 global_load_lds calls, g=0/1)
    auto stageA = [&](int T, int h, int pbuf) {
        const char* src = (const char*)wq + (long)((T * 2 + h) * 2) * 8192 + abase;
        _Float16* dst = smem + pbuf * 32768 + (h * 128 + wv * 8) * 64;
        __builtin_amdgcn_global_load_lds((AS1 void*)src,          (AS3 void*)dst,          16, 0, 0);
        __builtin_amdgcn_global_load_lds((AS1 void*)(src + 8192), (AS3 void*)(dst + 4096), 16, 0, 0);
    };
    // stage one B half-tile (2 calls, g=0/1)
    auto stageB = [&](int T, int h, int pbuf) {
        const int rs = T >> 1, kt = T & 1;
        const int r  = (rs * 11) >> 5;          // rs/3 for rs in [0,9)
        const int s2 = rs - r * 3;
        const long toff = (long)(r * 58 + s2) * 256 + kt * 128;
        const char* xb = (const char*)xp + toff;
        _Float16* dst = smem + pbuf * 32768 + 16384 + (h * 128 + wv * 8) * 64;
        __builtin_amdgcn_global_load_lds((AS1 void*)(xb + pbB[h * 2 + 0]), (AS3 void*)dst,          16, 0, 0);
        __builtin_amdgcn_global_load_lds((AS1 void*)(xb + pbB[h * 2 + 1]), (AS3 void*)(dst + 4096), 16, 0, 0);
    };

    const int arow = wm * 128 + (l & 15);
    const int brow = wn * 64 + (l & 15);

    // quadrant q: mi in {2q,2q+1}, all ni, kk. q is a literal at expansion -> static acc idx.
    #define QUAD(q) { \
        __builtin_amdgcn_s_setprio(1); \
        _Pragma("unroll") for (int i = 0; i < 2; ++i) { \
            const int mi = (q) * 2 + i; \
            const half8 af0 = *(const half8*)(As + (arow + mi * 16) * 64 + ((0 + l47) ^ l7) * 8); \
            const half8 af1 = *(const half8*)(As + (arow + mi * 16) * 64 + ((4 + l47) ^ l7) * 8); \
            _Pragma("unroll") for (int ni = 0; ni < 4; ++ni) { \
                acc[mi][ni] = __builtin_amdgcn_mfma_f32_16x16x32_f16(af0, bf[ni][0], acc[mi][ni], 0, 0, 0); \
                acc[mi][ni] = __builtin_amdgcn_mfma_f32_16x16x32_f16(af1, bf[ni][1], acc[mi][ni], 0, 0, 0); \
            } \
        } \
        __builtin_amdgcn_s_setprio(0); \
    }

    // prologue: stage K-tile 0 into buf 0 (8 calls)
    stageA(0, 0, 0); stageA(0, 1, 0); stageB(0, 0, 0); stageB(0, 1, 0);

    #pragma unroll 2
    for (int T = 0; T < 18; ++T) {
        const int pb = T & 1;
        const _Float16* As = smem + pb * 32768;
        const _Float16* Bs = As + 16384;
        // ---- phase 0: fence prev readers, start staging T+1, wait T's data ----
        asm volatile("s_barrier" ::: "memory");          // all waves done reading buf pb^1
        if (T < 17) {
            stageA(T + 1, 0, pb ^ 1);
            asm volatile("s_waitcnt vmcnt(2)" ::: "memory");   // T's 8 calls retired; 2 of T+1 in flight
        } else {
            asm volatile("s_waitcnt vmcnt(0)" ::: "memory");
        }
        asm volatile("s_barrier" ::: "memory");          // T's data visible to all waves
        half8 bf[4][2];
        #pragma unroll
        for (int ni = 0; ni < 4; ++ni) {
            bf[ni][0] = *(const half8*)(Bs + (brow + ni * 16) * 64 + ((0 + l47) ^ l7) * 8);
            bf[ni][1] = *(const half8*)(Bs + (brow + ni * 16) * 64 + ((4 + l47) ^ l7) * 8);
        }
        QUAD(0)
        // ---- phase 1 ----
        if (T < 17) stageA(T + 1, 1, pb ^ 1);
        QUAD(1)
        // ---- phase 2 ----
        if (T < 17) stageB(T + 1, 0, pb ^ 1);
        QUAD(2)
        // ---- phase 3 ----
        if (T < 17) stageB(T + 1, 1, pb ^ 1);
        QUAD(3)
    }
    #undef QUAD

    // epilogue: D[row=(l>>4)*4+reg = filter][col=l&15 = pixel]
    #pragma unroll
    for (int mi = 0; mi < 8; ++mi) {
        const int kb = wm * 128 + mi * 16 + (l >> 4) * 4;
        #pragma unroll
        for (int rg = 0; rg < 4; ++rg) {
            const int k = kb + rg;
            const float bq = rintf(b[k] * 128.0f);
            #pragma unroll
            for (int ni = 0; ni < 4; ++ni) {
                const int pix = bx * 256 + wn * 64 + ni * 16 + (l & 15);
                const int n  = pix / IMG;
                const int pr = pix - n * IMG;
                out[((long)n * 256 + k) * IMG + pr] = acc[mi][ni][rg] * (1.0f / 128.0f) + bq;
            }
        }
    }
}

// ---------------- fallback (ws too small): direct conv, correct but slow ----------------
__global__ void conv_fallback_kernel(const float* __restrict__ x, const float* __restrict__ W,
                                     const float* __restrict__ b, float* __restrict__ out)
{
    __shared__ float wsm[1152];
    const int k = blockIdx.y;
    for (int i = threadIdx.x; i < 1152; i += 256)
        wsm[i] = rintf(W[k * 1152 + i] * 128.0f);
    __syncthreads();
    const int pix = blockIdx.x * 256 + threadIdx.x;
    const int n = pix / IMG, hw = pix % IMG;
    const int h = hw / 56, w = hw % 56;
    float acc = 0.0f;
    for (int c = 0; c < 128; ++c) {
        const float* xr = x + ((n * 128 + c) * 56) * 56;
        const float* wr = wsm + c * 9;
        #pragma unroll
        for (int r = 0; r < 3; ++r) {
            const int hh = h + r - 1;
            if ((unsigned)hh >= 56u) continue;
            #pragma unroll
            for (int s = 0; s < 3; ++s) {
                const int ww = w + s - 1;
                if ((unsigned)ww >= 56u) continue;
                acc += xr[hh * 56 + ww] * wr[r * 3 + s];
            }
        }
    }
    out[((long)n * 256 + k) * IMG + hw] = acc * (1.0f / 128.0f) + rintf(b[k] * 128.0f);
}

extern "C" void kernel_launch(void* const* d_in, const int* in_sizes, int n_in,
                              void* d_out, int out_size, void* d_ws, size_t ws_size,
                              hipStream_t stream) {
    const float* x = (const float*)d_in[0];
    const float* W = (const float*)d_in[1];
    const float* b = (const float*)d_in[2];
    float* out = (float*)d_out;

    const size_t need = (size_t)XP_ELEMS * 2 + (size_t)WQ_ELEMS * 2;   // 28,147,712 B
    if (ws_size >= need) {
        _Float16* xp = (_Float16*)d_ws;
        _Float16* wq = xp + XP_ELEMS;
        prep_kernel<<<2000, 256, 0, stream>>>(x, W, xp, wq);
        conv_mfma_kernel<<<dim3(392), 512, 0, stream>>>(xp, wq, b, out);
    } else {
        conv_fallback_kernel<<<dim3(392, 256), 256, 0, stream>>>(x, W, b, out);
    }
}